// Round 1
// baseline (1030.528 us; speedup 1.0000x reference)
//
#include <hip/hip_runtime.h>

constexpr int kNV  = 40962;
constexpr int kNF  = 81920;
constexpr int kNVP = 10242;
constexpr int kB   = 2;
constexpr float kEPS  = 1e-5f;
constexpr int kBNN   = kB * kNV;              // 81924
constexpr float kInvN = 1.0f / (float)kBNN;

// ---------------- zero stats ----------------
__global__ void zero_stats_k(float* stats) {
    int t = threadIdx.x;
    if (t < 512) stats[t] = 0.f;
}

// ---------------- build xin_t (B,NV,64) with ones-pad, and X_t[...,0:64] = x2^T ----------------
__global__ void transpose_in_k(const float* __restrict__ x1, const float* __restrict__ x2,
                               float* __restrict__ xin_t, float* __restrict__ X_t) {
    const int total = kB * kNV * 64;
    for (int idx = blockIdx.x * blockDim.x + threadIdx.x; idx < total;
         idx += gridDim.x * blockDim.x) {
        int c  = idx & 63;
        int bv = idx >> 6;
        int v  = bv % kNV;
        int b  = bv / kNV;
        float xi = 1.0f;
        if (v < kNVP) xi = x1[(b * 64 + c) * kNVP + v];
        xin_t[idx] = xi;
        X_t[(size_t)bv * 128 + c] = x2[(size_t)(b * 64 + c) * kNV + v];
    }
}

// ---------------- face kernel: ge/gn (B,NF,64) ----------------
__global__ void face_k(const float* __restrict__ src,            // (B,NV,64)
                       const int* __restrict__ Gc, const float* __restrict__ Gv,   // (3NF,3)
                       const float* __restrict__ ew, const float* __restrict__ ns, // (NF,3)
                       float* __restrict__ ge, float* __restrict__ gn) {
    int lane = threadIdx.x & 63;
    int wavesPerBlock = blockDim.x >> 6;
    int wave   = blockIdx.x * wavesPerBlock + (threadIdx.x >> 6);
    int nWaves = gridDim.x * wavesPerBlock;
    for (int task = wave; task < kB * kNF; task += nWaves) {
        int f = task % kNF;
        int b = task / kNF;
        const float* sb = src + (size_t)b * kNV * 64;
        float accE = 0.f, accN = 0.f;
#pragma unroll
        for (int j = 0; j < 3; ++j) {
            int r = j * kNF + f;
            float g = 0.f;
#pragma unroll
            for (int k = 0; k < 3; ++k) {
                int col   = Gc[r * 3 + k];
                float val = Gv[r * 3 + k];
                g = fmaf(val, sb[(size_t)col * 64 + lane], g);
            }
            accE = fmaf(g, ew[f * 3 + j], accE);
            accN = fmaf(g, ns[f * 3 + j], accN);
        }
        ge[(size_t)task * 64 + lane] = accE;
        gn[(size_t)task * 64 + lane] = accN;
    }
}

// ---------------- vertex kernel: meshconv finish + dense (64 out x 256 in) ----------------
template <bool STATS>
__global__ __launch_bounds__(512) void vertex_k(
    const float* __restrict__ src,                               // (B,NV,64)
    const float* __restrict__ ge, const float* __restrict__ gn,  // (B,NF,64)
    const int* __restrict__ Lc, const float* __restrict__ Lv,    // (NV,7)
    const int* __restrict__ Fc, const float* __restrict__ Fv,    // (NV,6)
    const float* __restrict__ coeffs,                            // (64,64,4)
    const float* __restrict__ bias,                              // (64)
    float* __restrict__ out, int outStride,                      // out[task*outStride + o]
    float* __restrict__ stats)                                   // [2][64] or null
{
    __shared__ __align__(16) float cLds[64 * 256];  // [i][o][k]
    __shared__ __align__(16) float fLds[8 * 256];   // [wave][i*4+k]
    int tid = threadIdx.x;
    for (int j = tid; j < 64 * 256; j += 512) {     // coeffs (o,i,k) -> (i,o,k)
        int o = j >> 8;
        int rem = j & 255;
        int i = rem >> 2, k = rem & 3;
        cLds[i * 256 + o * 4 + k] = coeffs[j];
    }
    __syncthreads();

    int lane  = tid & 63;
    int wslot = tid >> 6;
    int wave   = blockIdx.x * 8 + wslot;
    int nWaves = gridDim.x * 8;
    int nIter  = (kB * kNV + nWaves - 1) / nWaves;
    float s = 0.f, sq = 0.f;
    const float bo = bias[lane];

    for (int it = 0; it < nIter; ++it) {
        int task   = wave + it * nWaves;
        bool valid = task < kB * kNV;
        float x0 = 0.f, lap = 0.f, gew = 0.f, gns = 0.f;
        if (valid) {
            int v = task % kNV;
            int b = task / kNV;
            const float* sb  = src + (size_t)b * kNV * 64;
            const float* geb = ge  + (size_t)b * kNF * 64;
            const float* gnb = gn  + (size_t)b * kNF * 64;
            x0 = src[(size_t)task * 64 + lane];
#pragma unroll
            for (int k = 0; k < 7; ++k) {
                int col = Lc[v * 7 + k];
                lap = fmaf(Lv[v * 7 + k], sb[(size_t)col * 64 + lane], lap);
            }
#pragma unroll
            for (int k = 0; k < 6; ++k) {
                int col = Fc[v * 6 + k];
                float w = Fv[v * 6 + k];
                gew = fmaf(w, geb[(size_t)col * 64 + lane], gew);
                gns = fmaf(w, gnb[(size_t)col * 64 + lane], gns);
            }
        }
        reinterpret_cast<float4*>(fLds)[wslot * 64 + lane] = make_float4(x0, lap, gew, gns);
        __syncthreads();
        float acc = bo;
        const float4* fl = reinterpret_cast<const float4*>(fLds) + wslot * 64;
        const float4* cl = reinterpret_cast<const float4*>(cLds);
#pragma unroll 8
        for (int i = 0; i < 64; ++i) {
            float4 fv = fl[i];
            float4 wv = cl[i * 64 + lane];
            acc = fmaf(fv.x, wv.x, acc);
            acc = fmaf(fv.y, wv.y, acc);
            acc = fmaf(fv.z, wv.z, acc);
            acc = fmaf(fv.w, wv.w, acc);
        }
        __syncthreads();
        if (valid) {
            out[(size_t)task * outStride + lane] = acc;
            if (STATS) { s += acc; sq += acc * acc; }
        }
    }
    if (STATS) {
        atomicAdd(&stats[lane], s);
        atomicAdd(&stats[64 + lane], sq);
    }
}

// ---------------- 1x1 conv kernel: (B,NV,CIN) -> one or two (B,NV,64), with BN stats ----------------
template <int CIN, bool DUAL>
__global__ __launch_bounds__(512) void pconv_k(
    const float* __restrict__ X,
    const float* __restrict__ W1, const float* __restrict__ b1,
    const float* __restrict__ W2, const float* __restrict__ b2,
    float* __restrict__ O1, float* __restrict__ O2,
    float* __restrict__ stats1, float* __restrict__ stats2)
{
    __shared__ __align__(16) float w1Lds[CIN * 64];
    __shared__ __align__(16) float w2Lds[DUAL ? CIN * 64 : 4];
    __shared__ __align__(16) float xLds[8 * CIN];
    int tid = threadIdx.x;
    for (int j = tid; j < 64 * CIN; j += 512) {
        int o = j / CIN;
        int c = j & (CIN - 1);
        w1Lds[(c >> 2) * 256 + o * 4 + (c & 3)] = W1[j];
        if (DUAL) w2Lds[(c >> 2) * 256 + o * 4 + (c & 3)] = W2[j];
    }
    __syncthreads();

    int lane  = tid & 63;
    int wslot = tid >> 6;
    int wave   = blockIdx.x * 8 + wslot;
    int nWaves = gridDim.x * 8;
    int nIter  = (kB * kNV + nWaves - 1) / nWaves;
    float s1 = 0.f, sq1 = 0.f, s2 = 0.f, sq2 = 0.f;
    const float bo1 = b1[lane];
    float bo2 = 0.f;
    if (DUAL) bo2 = b2[lane];

    for (int it = 0; it < nIter; ++it) {
        int task   = wave + it * nWaves;
        bool valid = task < kB * kNV;
        if (valid) {
            xLds[wslot * CIN + lane] = X[(size_t)task * CIN + lane];
            if (CIN == 128) xLds[wslot * CIN + 64 + lane] = X[(size_t)task * CIN + 64 + lane];
        }
        __syncthreads();
        float acc1 = bo1, acc2 = bo2;
        const float4* xl  = reinterpret_cast<const float4*>(xLds) + wslot * (CIN / 4);
        const float4* wl1 = reinterpret_cast<const float4*>(w1Lds);
        const float4* wl2 = reinterpret_cast<const float4*>(w2Lds);
#pragma unroll 8
        for (int cc = 0; cc < CIN / 4; ++cc) {
            float4 xv = xl[cc];
            float4 a = wl1[cc * 64 + lane];
            acc1 = fmaf(xv.x, a.x, acc1);
            acc1 = fmaf(xv.y, a.y, acc1);
            acc1 = fmaf(xv.z, a.z, acc1);
            acc1 = fmaf(xv.w, a.w, acc1);
            if (DUAL) {
                float4 bb = wl2[cc * 64 + lane];
                acc2 = fmaf(xv.x, bb.x, acc2);
                acc2 = fmaf(xv.y, bb.y, acc2);
                acc2 = fmaf(xv.z, bb.z, acc2);
                acc2 = fmaf(xv.w, bb.w, acc2);
            }
        }
        __syncthreads();
        if (valid) {
            O1[(size_t)task * 64 + lane] = acc1;
            s1 += acc1; sq1 += acc1 * acc1;
            if (DUAL) {
                O2[(size_t)task * 64 + lane] = acc2;
                s2 += acc2; sq2 += acc2 * acc2;
            }
        }
    }
    atomicAdd(&stats1[lane], s1);
    atomicAdd(&stats1[64 + lane], sq1);
    if (DUAL) {
        atomicAdd(&stats2[lane], s2);
        atomicAdd(&stats2[64 + lane], sq2);
    }
}

// ---------------- BN (train) + ReLU, elementwise channel-last ----------------
__global__ void bn_relu_k(const float* __restrict__ P, const float* __restrict__ stats,
                          const float* __restrict__ g, const float* __restrict__ bb,
                          float* __restrict__ out) {
    const int total = kB * kNV * 64;
    for (int idx = blockIdx.x * blockDim.x + threadIdx.x; idx < total;
         idx += gridDim.x * blockDim.x) {
        int o = idx & 63;
        float mean  = stats[o] * kInvN;
        float var   = stats[64 + o] * kInvN - mean * mean;
        float scale = g[o] * rsqrtf(var + kEPS);
        float shift = bb[o] - mean * scale;
        float val = fmaf(P[idx], scale, shift);
        out[idx] = val > 0.f ? val : 0.f;
    }
}

// ---------------- final: relu(bn3(P3) + bns(S)) -> out (B,64,NV) channel-major ----------------
__global__ __launch_bounds__(256) void final_k(
    const float* __restrict__ P3, const float* __restrict__ S,
    const float* __restrict__ st3, const float* __restrict__ stS,
    const float* __restrict__ g3, const float* __restrict__ b3,
    const float* __restrict__ gs, const float* __restrict__ bs,
    float* __restrict__ out)
{
    __shared__ float lds[64 * 65];
    const int tilesPerB = (kNV + 63) / 64;  // 641
    int tile = blockIdx.x % tilesPerB;
    int b    = blockIdx.x / tilesPerB;
    int v0   = tile * 64;
    int tid  = threadIdx.x;
#pragma unroll
    for (int r = 0; r < 16; ++r) {
        int idx = r * 256 + tid;
        int vl = idx >> 6, o = idx & 63;
        int v = v0 + vl;
        if (v < kNV) {
            float m3  = st3[o] * kInvN;
            float vr3 = st3[64 + o] * kInvN - m3 * m3;
            float sc3 = g3[o] * rsqrtf(vr3 + kEPS);
            float sh3 = b3[o] - m3 * sc3;
            float mS  = stS[o] * kInvN;
            float vrS = stS[64 + o] * kInvN - mS * mS;
            float scS = gs[o] * rsqrtf(vrS + kEPS);
            float shS = bs[o] - mS * scS;
            size_t base = (size_t)(b * kNV + v) * 64 + o;
            float val = fmaf(P3[base], sc3, sh3) + fmaf(S[base], scS, shS);
            lds[vl * 65 + o] = val > 0.f ? val : 0.f;
        }
    }
    __syncthreads();
#pragma unroll
    for (int r = 0; r < 16; ++r) {
        int idx = r * 256 + tid;
        int o = idx >> 6, vl = idx & 63;
        int v = v0 + vl;
        if (v < kNV) out[(size_t)(b * 64 + o) * kNV + v] = lds[vl * 65 + o];
    }
}

extern "C" void kernel_launch(void* const* d_in, const int* in_sizes, int n_in,
                              void* d_out, int out_size, void* d_ws, size_t ws_size,
                              hipStream_t stream) {
    const float* x1  = (const float*)d_in[0];
    const float* x2  = (const float*)d_in[1];
    const int*   Gc  = (const int*)d_in[2];
    const float* Gv  = (const float*)d_in[3];
    const int*   Lc  = (const int*)d_in[4];
    const float* Lv  = (const float*)d_in[5];
    const int*   Fc  = (const int*)d_in[6];
    const float* Fv  = (const float*)d_in[7];
    const float* ew  = (const float*)d_in[8];
    const float* ns  = (const float*)d_in[9];
    // d_in[10] = v2p (identity arange, unused)
    const float* upC = (const float*)d_in[11];
    const float* upB = (const float*)d_in[12];
    const float* c2C = (const float*)d_in[13];
    const float* c2B = (const float*)d_in[14];
    const float* w1  = (const float*)d_in[15];
    const float* b1  = (const float*)d_in[16];
    const float* w3  = (const float*)d_in[17];
    const float* b3  = (const float*)d_in[18];
    const float* wsw = (const float*)d_in[19];
    const float* wsb = (const float*)d_in[20];
    const float* bn1g = (const float*)d_in[21];
    const float* bn1b = (const float*)d_in[22];
    const float* bn2g = (const float*)d_in[23];
    const float* bn2b = (const float*)d_in[24];
    const float* bn3g = (const float*)d_in[25];
    const float* bn3b = (const float*)d_in[26];
    const float* bnsg = (const float*)d_in[27];
    const float* bnsb = (const float*)d_in[28];

    float* ws = (float*)d_ws;
    float* stats = ws;  // 4 sets x [sum(64), sumsq(64)] = 512 floats
    size_t off = 512;
    float* xin_t = ws + off; off += (size_t)kB * kNV * 64;    // later reused as h2
    float* X_t   = ws + off; off += (size_t)kB * kNV * 128;   // later reused as P3
    float* ge    = ws + off; off += (size_t)kB * kNF * 64;
    float* gn    = ws + off; off += (size_t)kB * kNF * 64;
    float* P     = ws + off; off += (size_t)kB * kNV * 64;    // P1 then P2
    float* Sbuf  = ws + off; off += (size_t)kB * kNV * 64;
    float* h     = ws + off; off += (size_t)kB * kNV * 64;
    float* h2 = xin_t;
    float* P3 = X_t;
    float* out = (float*)d_out;

    zero_stats_k<<<1, 512, 0, stream>>>(stats);
    transpose_in_k<<<2048, 256, 0, stream>>>(x1, x2, xin_t, X_t);
    // mesh_conv #1 (up): on xin
    face_k<<<4096, 256, 0, stream>>>(xin_t, Gc, Gv, ew, ns, ge, gn);
    vertex_k<false><<<1024, 512, 0, stream>>>(xin_t, ge, gn, Lc, Lv, Fc, Fv, upC, upB,
                                              X_t + 64, 128, nullptr);
    // conv1 + convs on x = [x2, xu]
    pconv_k<128, true><<<1024, 512, 0, stream>>>(X_t, w1, b1, wsw, wsb, P, Sbuf,
                                                 stats + 0 * 128, stats + 3 * 128);
    bn_relu_k<<<2048, 256, 0, stream>>>(P, stats + 0 * 128, bn1g, bn1b, h);
    // mesh_conv #2 (c2): on h
    face_k<<<4096, 256, 0, stream>>>(h, Gc, Gv, ew, ns, ge, gn);
    vertex_k<true><<<1024, 512, 0, stream>>>(h, ge, gn, Lc, Lv, Fc, Fv, c2C, c2B,
                                             P, 64, stats + 1 * 128);
    bn_relu_k<<<2048, 256, 0, stream>>>(P, stats + 1 * 128, bn2g, bn2b, h2);
    // conv3 on h2
    pconv_k<64, false><<<1024, 512, 0, stream>>>(h2, w3, b3, nullptr, nullptr, P3, nullptr,
                                                 stats + 2 * 128, nullptr);
    final_k<<<2 * 641, 256, 0, stream>>>(P3, Sbuf, stats + 2 * 128, stats + 3 * 128,
                                         bn3g, bn3b, bnsg, bnsb, out);
}

// Round 2
// 732.885 us; speedup vs baseline: 1.4061x; 1.4061x over previous
//
#include <hip/hip_runtime.h>

constexpr int kNV  = 40962;
constexpr int kNF  = 81920;
constexpr int kNVP = 10242;
constexpr int kB   = 2;
constexpr float kEPS  = 1e-5f;
constexpr int kBNN   = kB * kNV;              // 81924
constexpr float kInvN = 1.0f / (float)kBNN;

__device__ __forceinline__ float bflo(unsigned u) { return __uint_as_float(u << 16); }
__device__ __forceinline__ float bfhi(unsigned u) { return __uint_as_float(u & 0xffff0000u); }
__device__ __forceinline__ unsigned packbf(float a, float b) {
    unsigned ua = __float_as_uint(a), ub = __float_as_uint(b);
    ua += 0x7fffu + ((ua >> 16) & 1u);
    ub += 0x7fffu + ((ub >> 16) & 1u);
    return (ua >> 16) | (ub & 0xffff0000u);
}

// ---------------- zero stats ----------------
__global__ void zero_stats_k(float* stats) {
    int t = threadIdx.x;
    if (t < 512) stats[t] = 0.f;
}

// ---------------- tiled transpose: x1 -> xin_t (ones-pad), x2 -> X_t[:, :64] ----------------
__global__ __launch_bounds__(256) void transpose_in_k(const float* __restrict__ x1,
                                                      const float* __restrict__ x2,
                                                      float* __restrict__ xin_t,
                                                      float* __restrict__ X_t) {
    __shared__ float t1[64 * 65];
    __shared__ float t2[64 * 65];
    const int tilesPerB = (kNV + 63) / 64;  // 641
    int tile = blockIdx.x % tilesPerB;
    int b    = blockIdx.x / tilesPerB;
    int v0   = tile * 64;
    int tid  = threadIdx.x;
    bool hasX1 = v0 < kNVP;
#pragma unroll
    for (int r = 0; r < 16; ++r) {
        int idx = r * 256 + tid;
        int c = idx >> 6, vl = idx & 63;
        int v = v0 + vl;
        if (v < kNV) {
            t2[vl * 65 + c] = x2[(size_t)(b * 64 + c) * kNV + v];
            if (hasX1) t1[vl * 65 + c] = (v < kNVP) ? x1[(size_t)(b * 64 + c) * kNVP + v] : 1.0f;
        }
    }
    __syncthreads();
#pragma unroll
    for (int r = 0; r < 16; ++r) {
        int idx = r * 256 + tid;
        int vl = idx >> 6, c = idx & 63;
        int v = v0 + vl;
        if (v < kNV) {
            X_t[(size_t)(b * kNV + v) * 128 + c]  = t2[vl * 65 + c];
            xin_t[(size_t)(b * kNV + v) * 64 + c] = hasX1 ? t1[vl * 65 + c] : 1.0f;
        }
    }
}

// ---------------- face kernel: packed bf16 (ge,gn) per face, optional fused BN+ReLU input ----------------
template <bool BN>
__global__ __launch_bounds__(256) void face_k(
    const float* __restrict__ src,                                   // (B,NV,64) pre-BN
    const int* __restrict__ Gc, const float* __restrict__ Gv,        // (3NF,3)
    const float* __restrict__ ew, const float* __restrict__ ns,      // (NF,3)
    const float* __restrict__ st, const float* __restrict__ bg, const float* __restrict__ bb,
    unsigned* __restrict__ gegn)                                     // (B*NF,64) bf16x2
{
    int lane = threadIdx.x & 63;
    int wave = blockIdx.x * 4 + (threadIdx.x >> 6);
    int nW   = gridDim.x * 4;
    float sc = 0.f, sh = 0.f;
    if constexpr (BN) {
        float m   = st[lane] * kInvN;
        float var = st[64 + lane] * kInvN - m * m;
        sc = bg[lane] * rsqrtf(var + kEPS);
        sh = bb[lane] - m * sc;
    }
    const int nG = (kB * kNF) / 4;  // 40960, exact
    for (int g = wave; g < nG; g += nW) {
        int t0 = g * 4;
        float accE[4], accN[4];
#pragma unroll
        for (int t = 0; t < 4; ++t) {
            int task = t0 + t;
            int b = task >= kNF;
            int f = task - (b ? kNF : 0);
            const float* sb = src + (size_t)b * kNV * 64;
            float aE = 0.f, aN = 0.f;
#pragma unroll
            for (int j = 0; j < 3; ++j) {
                int r = j * kNF + f;
                float gacc = 0.f;
#pragma unroll
                for (int k = 0; k < 3; ++k) {
                    int col   = Gc[r * 3 + k];
                    float val = Gv[r * 3 + k];
                    float xv  = sb[(size_t)col * 64 + lane];
                    if constexpr (BN) { xv = fmaf(xv, sc, sh); xv = xv > 0.f ? xv : 0.f; }
                    gacc = fmaf(val, xv, gacc);
                }
                aE = fmaf(gacc, ew[f * 3 + j], aE);
                aN = fmaf(gacc, ns[f * 3 + j], aN);
            }
            accE[t] = aE; accN[t] = aN;
        }
#pragma unroll
        for (int t = 0; t < 4; ++t)
            gegn[(size_t)(t0 + t) * 64 + lane] = packbf(accE[t], accN[t]);
    }
}

// ---------------- vertex kernel: meshconv finish + dense 64x256, 4 tasks/wave, no barriers ----------------
template <bool STATS, bool BN>
__global__ __launch_bounds__(512, 4) void vertex_k(
    const float* __restrict__ src,                                   // (B,NV,64) pre-BN
    const unsigned* __restrict__ gegn,                               // (B*NF,64) bf16x2
    const int* __restrict__ Lc, const float* __restrict__ Lv,        // (NV,7)
    const int* __restrict__ Fc, const float* __restrict__ Fv,        // (NV,6)
    const float* __restrict__ coeffs, const float* __restrict__ bias,// (64,64,4),(64)
    const float* __restrict__ st, const float* __restrict__ bg, const float* __restrict__ bb,
    float* __restrict__ out, int outStride, float* __restrict__ stats)
{
    __shared__ __align__(16) uint2  cLds[64 * 64];    // [i*64+o] bf16x4, 32 KB
    __shared__ __align__(16) float4 fLds[8 * 4 * 64]; // [wslot][t][i], 32 KB
    int tid = threadIdx.x;
    for (int j = tid; j < 64 * 64; j += 512) {        // coeffs (o,i,k) -> [i][o] packed
        int i = j & 63, o = j >> 6;
        float4 cf = *reinterpret_cast<const float4*>(coeffs + (size_t)(o * 64 + i) * 4);
        cLds[i * 64 + o] = make_uint2(packbf(cf.x, cf.y), packbf(cf.z, cf.w));
    }
    __syncthreads();

    int lane  = tid & 63;
    int wslot = tid >> 6;
    int wave  = blockIdx.x * 8 + wslot;
    int nW    = gridDim.x * 8;
    float sc = 0.f, sh = 0.f;
    if constexpr (BN) {
        float m   = st[lane] * kInvN;
        float var = st[64 + lane] * kInvN - m * m;
        sc = bg[lane] * rsqrtf(var + kEPS);
        sh = bb[lane] - m * sc;
    }
    const float bo = bias[lane];
    float s = 0.f, sq = 0.f;
    float4* fme = fLds + wslot * 4 * 64;
    const int nG = kBNN / 4;  // 20481, exact

    for (int g = wave; g < nG; g += nW) {
        int t0 = g * 4;
#pragma unroll
        for (int t = 0; t < 4; ++t) {
            int task = t0 + t;
            int b = task >= kNV;
            int v = task - (b ? kNV : 0);
            const float* sb = src + (size_t)b * kNV * 64;
            const unsigned* gb = gegn + (size_t)b * kNF * 64;
            float xv = src[(size_t)task * 64 + lane];
            if constexpr (BN) { xv = fmaf(xv, sc, sh); xv = xv > 0.f ? xv : 0.f; }
            float lap = 0.f, gE = 0.f, gN = 0.f;
#pragma unroll
            for (int k = 0; k < 7; ++k) {
                int col = Lc[v * 7 + k];
                float xx = sb[(size_t)col * 64 + lane];
                if constexpr (BN) { xx = fmaf(xx, sc, sh); xx = xx > 0.f ? xx : 0.f; }
                lap = fmaf(Lv[v * 7 + k], xx, lap);
            }
#pragma unroll
            for (int k = 0; k < 6; ++k) {
                int col = Fc[v * 6 + k];
                float w = Fv[v * 6 + k];
                unsigned u = gb[(size_t)col * 64 + lane];
                gE = fmaf(w, bflo(u), gE);
                gN = fmaf(w, bfhi(u), gN);
            }
            fme[t * 64 + lane] = make_float4(xv, lap, gE, gN);
        }
        // intra-wave LDS: DS pipeline is in-order per wave -> no barrier needed
        float a0 = bo, a1 = bo, a2 = bo, a3 = bo;
#pragma unroll 8
        for (int i = 0; i < 64; ++i) {
            uint2 w = cLds[i * 64 + lane];
            float w0 = bflo(w.x), w1 = bfhi(w.x), w2 = bflo(w.y), w3 = bfhi(w.y);
            float4 v0 = fme[0 * 64 + i], v1 = fme[1 * 64 + i];
            float4 v2 = fme[2 * 64 + i], v3 = fme[3 * 64 + i];
            a0 = fmaf(v0.x, w0, a0); a0 = fmaf(v0.y, w1, a0); a0 = fmaf(v0.z, w2, a0); a0 = fmaf(v0.w, w3, a0);
            a1 = fmaf(v1.x, w0, a1); a1 = fmaf(v1.y, w1, a1); a1 = fmaf(v1.z, w2, a1); a1 = fmaf(v1.w, w3, a1);
            a2 = fmaf(v2.x, w0, a2); a2 = fmaf(v2.y, w1, a2); a2 = fmaf(v2.z, w2, a2); a2 = fmaf(v2.w, w3, a2);
            a3 = fmaf(v3.x, w0, a3); a3 = fmaf(v3.y, w1, a3); a3 = fmaf(v3.z, w2, a3); a3 = fmaf(v3.w, w3, a3);
        }
        out[(size_t)(t0 + 0) * outStride + lane] = a0;
        out[(size_t)(t0 + 1) * outStride + lane] = a1;
        out[(size_t)(t0 + 2) * outStride + lane] = a2;
        out[(size_t)(t0 + 3) * outStride + lane] = a3;
        if constexpr (STATS) {
            s  += a0 + a1 + a2 + a3;
            sq += a0 * a0 + a1 * a1 + a2 * a2 + a3 * a3;
        }
    }
    if constexpr (STATS) {
        atomicAdd(&stats[lane], s);
        atomicAdd(&stats[64 + lane], sq);
    }
}

// ---------------- 1x1 conv: 4 tasks/wave, bf16 weights in LDS, no barriers, optional input BN ----------------
template <int CIN, bool DUAL, bool BN>
__global__ __launch_bounds__(512, 4) void pconv_k(
    const float* __restrict__ X,
    const float* __restrict__ stI, const float* __restrict__ gI, const float* __restrict__ bI,
    const float* __restrict__ W1, const float* __restrict__ b1,
    const float* __restrict__ W2, const float* __restrict__ b2,
    float* __restrict__ O1, float* __restrict__ O2,
    float* __restrict__ stats1, float* __restrict__ stats2)
{
    constexpr int CC = CIN / 4;
    __shared__ __align__(16) uint2  w1L[CC * 64];
    __shared__ __align__(16) uint2  w2L[DUAL ? CC * 64 : 1];
    __shared__ __align__(16) float4 xL[8 * 4 * CC];
    int tid = threadIdx.x;
    for (int j = tid; j < CC * 64; j += 512) {
        int cc = j & (CC - 1), o = j / CC;
        float4 wf = *reinterpret_cast<const float4*>(W1 + (size_t)o * CIN + cc * 4);
        w1L[cc * 64 + o] = make_uint2(packbf(wf.x, wf.y), packbf(wf.z, wf.w));
        if constexpr (DUAL) {
            float4 wg = *reinterpret_cast<const float4*>(W2 + (size_t)o * CIN + cc * 4);
            w2L[cc * 64 + o] = make_uint2(packbf(wg.x, wg.y), packbf(wg.z, wg.w));
        }
    }
    __syncthreads();

    int lane  = tid & 63;
    int wslot = tid >> 6;
    int wave  = blockIdx.x * 8 + wslot;
    int nW    = gridDim.x * 8;
    float scI = 0.f, shI = 0.f;
    if constexpr (BN) {  // only used with CIN==64
        float m   = stI[lane] * kInvN;
        float var = stI[64 + lane] * kInvN - m * m;
        scI = gI[lane] * rsqrtf(var + kEPS);
        shI = bI[lane] - m * scI;
    }
    const float bo1 = b1[lane];
    float bo2 = 0.f;
    if constexpr (DUAL) bo2 = b2[lane];
    float s1 = 0.f, sq1 = 0.f, s2 = 0.f, sq2 = 0.f;
    float* xme = reinterpret_cast<float*>(xL + wslot * 4 * CC);
    const float4* xme4 = xL + wslot * 4 * CC;
    const int nG = kBNN / 4;

    for (int g = wave; g < nG; g += nW) {
        int t0 = g * 4;
#pragma unroll
        for (int t = 0; t < 4; ++t) {
            int task = t0 + t;
            float xv = X[(size_t)task * CIN + lane];
            if constexpr (BN) { xv = fmaf(xv, scI, shI); xv = xv > 0.f ? xv : 0.f; }
            xme[t * CIN + lane] = xv;
            if constexpr (CIN == 128) xme[t * CIN + 64 + lane] = X[(size_t)task * CIN + 64 + lane];
        }
        float a1_[4] = {bo1, bo1, bo1, bo1};
        float a2_[4] = {bo2, bo2, bo2, bo2};
#pragma unroll 8
        for (int cc = 0; cc < CC; ++cc) {
            uint2 u = w1L[cc * 64 + lane];
            float w0 = bflo(u.x), w1v = bfhi(u.x), w2v = bflo(u.y), w3v = bfhi(u.y);
            float4 x0 = xme4[0 * CC + cc], x1 = xme4[1 * CC + cc];
            float4 x2 = xme4[2 * CC + cc], x3 = xme4[3 * CC + cc];
            a1_[0] = fmaf(x0.x, w0, a1_[0]); a1_[0] = fmaf(x0.y, w1v, a1_[0]); a1_[0] = fmaf(x0.z, w2v, a1_[0]); a1_[0] = fmaf(x0.w, w3v, a1_[0]);
            a1_[1] = fmaf(x1.x, w0, a1_[1]); a1_[1] = fmaf(x1.y, w1v, a1_[1]); a1_[1] = fmaf(x1.z, w2v, a1_[1]); a1_[1] = fmaf(x1.w, w3v, a1_[1]);
            a1_[2] = fmaf(x2.x, w0, a1_[2]); a1_[2] = fmaf(x2.y, w1v, a1_[2]); a1_[2] = fmaf(x2.z, w2v, a1_[2]); a1_[2] = fmaf(x2.w, w3v, a1_[2]);
            a1_[3] = fmaf(x3.x, w0, a1_[3]); a1_[3] = fmaf(x3.y, w1v, a1_[3]); a1_[3] = fmaf(x3.z, w2v, a1_[3]); a1_[3] = fmaf(x3.w, w3v, a1_[3]);
            if constexpr (DUAL) {
                uint2 u2 = w2L[cc * 64 + lane];
                float q0 = bflo(u2.x), q1 = bfhi(u2.x), q2 = bflo(u2.y), q3 = bfhi(u2.y);
                a2_[0] = fmaf(x0.x, q0, a2_[0]); a2_[0] = fmaf(x0.y, q1, a2_[0]); a2_[0] = fmaf(x0.z, q2, a2_[0]); a2_[0] = fmaf(x0.w, q3, a2_[0]);
                a2_[1] = fmaf(x1.x, q0, a2_[1]); a2_[1] = fmaf(x1.y, q1, a2_[1]); a2_[1] = fmaf(x1.z, q2, a2_[1]); a2_[1] = fmaf(x1.w, q3, a2_[1]);
                a2_[2] = fmaf(x2.x, q0, a2_[2]); a2_[2] = fmaf(x2.y, q1, a2_[2]); a2_[2] = fmaf(x2.z, q2, a2_[2]); a2_[2] = fmaf(x2.w, q3, a2_[2]);
                a2_[3] = fmaf(x3.x, q0, a2_[3]); a2_[3] = fmaf(x3.y, q1, a2_[3]); a2_[3] = fmaf(x3.z, q2, a2_[3]); a2_[3] = fmaf(x3.w, q3, a2_[3]);
            }
        }
#pragma unroll
        for (int t = 0; t < 4; ++t) {
            float a = a1_[t];
            O1[(size_t)(t0 + t) * 64 + lane] = a;
            s1 += a; sq1 += a * a;
            if constexpr (DUAL) {
                float c = a2_[t];
                O2[(size_t)(t0 + t) * 64 + lane] = c;
                s2 += c; sq2 += c * c;
            }
        }
    }
    atomicAdd(&stats1[lane], s1);
    atomicAdd(&stats1[64 + lane], sq1);
    if constexpr (DUAL) {
        atomicAdd(&stats2[lane], s2);
        atomicAdd(&stats2[64 + lane], sq2);
    }
}

// ---------------- final: relu(bn3(P3) + bns(S)) -> out (B,64,NV) channel-major ----------------
__global__ __launch_bounds__(256) void final_k(
    const float* __restrict__ P3, const float* __restrict__ S,
    const float* __restrict__ st3, const float* __restrict__ stS,
    const float* __restrict__ g3, const float* __restrict__ b3,
    const float* __restrict__ gs, const float* __restrict__ bs,
    float* __restrict__ out)
{
    __shared__ float lds[64 * 65];
    const int tilesPerB = (kNV + 63) / 64;  // 641
    int tile = blockIdx.x % tilesPerB;
    int b    = blockIdx.x / tilesPerB;
    int v0   = tile * 64;
    int tid  = threadIdx.x;
#pragma unroll
    for (int r = 0; r < 16; ++r) {
        int idx = r * 256 + tid;
        int vl = idx >> 6, o = idx & 63;
        int v = v0 + vl;
        if (v < kNV) {
            float m3  = st3[o] * kInvN;
            float vr3 = st3[64 + o] * kInvN - m3 * m3;
            float sc3 = g3[o] * rsqrtf(vr3 + kEPS);
            float sh3 = b3[o] - m3 * sc3;
            float mS  = stS[o] * kInvN;
            float vrS = stS[64 + o] * kInvN - mS * mS;
            float scS = gs[o] * rsqrtf(vrS + kEPS);
            float shS = bs[o] - mS * scS;
            size_t base = (size_t)(b * kNV + v) * 64 + o;
            float val = fmaf(P3[base], sc3, sh3) + fmaf(S[base], scS, shS);
            lds[vl * 65 + o] = val > 0.f ? val : 0.f;
        }
    }
    __syncthreads();
#pragma unroll
    for (int r = 0; r < 16; ++r) {
        int idx = r * 256 + tid;
        int o = idx >> 6, vl = idx & 63;
        int v = v0 + vl;
        if (v < kNV) out[(size_t)(b * 64 + o) * kNV + v] = lds[vl * 65 + o];
    }
}

extern "C" void kernel_launch(void* const* d_in, const int* in_sizes, int n_in,
                              void* d_out, int out_size, void* d_ws, size_t ws_size,
                              hipStream_t stream) {
    const float* x1  = (const float*)d_in[0];
    const float* x2  = (const float*)d_in[1];
    const int*   Gc  = (const int*)d_in[2];
    const float* Gv  = (const float*)d_in[3];
    const int*   Lc  = (const int*)d_in[4];
    const float* Lv  = (const float*)d_in[5];
    const int*   Fc  = (const int*)d_in[6];
    const float* Fv  = (const float*)d_in[7];
    const float* ew  = (const float*)d_in[8];
    const float* ns  = (const float*)d_in[9];
    // d_in[10] = v2p (identity arange, unused)
    const float* upC = (const float*)d_in[11];
    const float* upB = (const float*)d_in[12];
    const float* c2C = (const float*)d_in[13];
    const float* c2B = (const float*)d_in[14];
    const float* w1  = (const float*)d_in[15];
    const float* b1  = (const float*)d_in[16];
    const float* w3  = (const float*)d_in[17];
    const float* b3  = (const float*)d_in[18];
    const float* wsw = (const float*)d_in[19];
    const float* wsb = (const float*)d_in[20];
    const float* bn1g = (const float*)d_in[21];
    const float* bn1b = (const float*)d_in[22];
    const float* bn2g = (const float*)d_in[23];
    const float* bn2b = (const float*)d_in[24];
    const float* bn3g = (const float*)d_in[25];
    const float* bn3b = (const float*)d_in[26];
    const float* bnsg = (const float*)d_in[27];
    const float* bnsb = (const float*)d_in[28];

    float* ws = (float*)d_ws;
    float* stats = ws;  // [bn1|bn2|bn3|bns] x [sum64, sumsq64]
    size_t off = 512;
    float* xin_t = ws + off; off += (size_t)kB * kNV * 64;   // reused as P2
    float* X_t   = ws + off; off += (size_t)kB * kNV * 128;
    unsigned* gegn = (unsigned*)(ws + off); off += (size_t)kB * kNF * 64;
    float* P1    = ws + off; off += (size_t)kB * kNV * 64;   // reused as P3
    float* Sbuf  = ws + off; off += (size_t)kB * kNV * 64;
    float* P2 = xin_t;
    float* P3 = P1;
    float* out = (float*)d_out;

    zero_stats_k<<<1, 512, 0, stream>>>(stats);
    transpose_in_k<<<2 * 641, 256, 0, stream>>>(x1, x2, xin_t, X_t);
    // mesh_conv #1 (up) on xin
    face_k<false><<<2048, 256, 0, stream>>>(xin_t, Gc, Gv, ew, ns,
                                            nullptr, nullptr, nullptr, gegn);
    vertex_k<false, false><<<512, 512, 0, stream>>>(xin_t, gegn, Lc, Lv, Fc, Fv, upC, upB,
                                                    nullptr, nullptr, nullptr,
                                                    X_t + 64, 128, nullptr);
    // conv1 + convs on X = [x2, xu]
    pconv_k<128, true, false><<<512, 512, 0, stream>>>(X_t, nullptr, nullptr, nullptr,
                                                       w1, b1, wsw, wsb, P1, Sbuf,
                                                       stats + 0 * 128, stats + 3 * 128);
    // mesh_conv #2 (c2) on h = relu(bn1(P1)), BN fused into consumers
    face_k<true><<<2048, 256, 0, stream>>>(P1, Gc, Gv, ew, ns,
                                           stats + 0 * 128, bn1g, bn1b, gegn);
    vertex_k<true, true><<<512, 512, 0, stream>>>(P1, gegn, Lc, Lv, Fc, Fv, c2C, c2B,
                                                  stats + 0 * 128, bn1g, bn1b,
                                                  P2, 64, stats + 1 * 128);
    // conv3 on h2 = relu(bn2(P2)), BN fused into input
    pconv_k<64, false, true><<<1024, 512, 0, stream>>>(P2, stats + 1 * 128, bn2g, bn2b,
                                                       w3, b3, nullptr, nullptr, P3, nullptr,
                                                       stats + 2 * 128, nullptr);
    final_k<<<2 * 641, 256, 0, stream>>>(P3, Sbuf, stats + 2 * 128, stats + 3 * 128,
                                         bn3g, bn3b, bnsg, bnsb, out);
}

// Round 3
// 438.088 us; speedup vs baseline: 2.3523x; 1.6729x over previous
//
#include <hip/hip_runtime.h>

constexpr int kNV  = 40962;
constexpr int kNF  = 81920;
constexpr int kNVP = 10242;
constexpr int kB   = 2;
constexpr float kEPS  = 1e-5f;
constexpr int kBNN   = kB * kNV;              // 81924
constexpr float kInvN = 1.0f / (float)kBNN;

__device__ __forceinline__ float bflo(unsigned u) { return __uint_as_float(u << 16); }
__device__ __forceinline__ float bfhi(unsigned u) { return __uint_as_float(u & 0xffff0000u); }
__device__ __forceinline__ unsigned packbf(float a, float b) {
    unsigned ua = __float_as_uint(a), ub = __float_as_uint(b);
    ua += 0x7fffu + ((ua >> 16) & 1u);
    ub += 0x7fffu + ((ub >> 16) & 1u);
    return (ua >> 16) | (ub & 0xffff0000u);
}

// ---------------- zero stats ----------------
__global__ void zero_stats_k(float* stats) {
    int t = threadIdx.x;
    if (t < 512) stats[t] = 0.f;
}

// ---------------- tiled transpose: x1 -> xin_t (ones-pad), x2 -> X_t[:, :64] ----------------
__global__ __launch_bounds__(256) void transpose_in_k(const float* __restrict__ x1,
                                                      const float* __restrict__ x2,
                                                      float* __restrict__ xin_t,
                                                      float* __restrict__ X_t) {
    __shared__ float t1[64 * 65];
    __shared__ float t2[64 * 65];
    const int tilesPerB = (kNV + 63) / 64;  // 641
    int tile = blockIdx.x % tilesPerB;
    int b    = blockIdx.x / tilesPerB;
    int v0   = tile * 64;
    int tid  = threadIdx.x;
    bool hasX1 = v0 < kNVP;
#pragma unroll
    for (int r = 0; r < 16; ++r) {
        int idx = r * 256 + tid;
        int c = idx >> 6, vl = idx & 63;
        int v = v0 + vl;
        if (v < kNV) {
            t2[vl * 65 + c] = x2[(size_t)(b * 64 + c) * kNV + v];
            if (hasX1) t1[vl * 65 + c] = (v < kNVP) ? x1[(size_t)(b * 64 + c) * kNVP + v] : 1.0f;
        }
    }
    __syncthreads();
#pragma unroll
    for (int r = 0; r < 16; ++r) {
        int idx = r * 256 + tid;
        int vl = idx >> 6, c = idx & 63;
        int v = v0 + vl;
        if (v < kNV) {
            X_t[(size_t)(b * kNV + v) * 128 + c]  = t2[vl * 65 + c];
            xin_t[(size_t)(b * kNV + v) * 64 + c] = hasX1 ? t1[vl * 65 + c] : 1.0f;
        }
    }
}

// ---------------- face kernel: packed bf16 (ge,gn) per face, optional fused BN+ReLU input ----------------
template <bool BN>
__global__ __launch_bounds__(256) void face_k(
    const float* __restrict__ src,                                   // (B,NV,64) pre-BN
    const int* __restrict__ Gc, const float* __restrict__ Gv,        // (3NF,3)
    const float* __restrict__ ew, const float* __restrict__ ns,      // (NF,3)
    const float* __restrict__ st, const float* __restrict__ bg, const float* __restrict__ bb,
    unsigned* __restrict__ gegn)                                     // (B*NF,64) bf16x2
{
    int lane = threadIdx.x & 63;
    int wave = blockIdx.x * 4 + (threadIdx.x >> 6);
    int nW   = gridDim.x * 4;
    float sc = 0.f, sh = 0.f;
    if constexpr (BN) {
        float m   = st[lane] * kInvN;
        float var = st[64 + lane] * kInvN - m * m;
        sc = bg[lane] * rsqrtf(var + kEPS);
        sh = bb[lane] - m * sc;
    }
    const int nG = (kB * kNF) / 4;  // 40960, exact
    for (int g = wave; g < nG; g += nW) {
        int t0 = g * 4;
        float accE[4], accN[4];
#pragma unroll
        for (int t = 0; t < 4; ++t) {
            int task = t0 + t;
            int b = task >= kNF;
            int f = task - (b ? kNF : 0);
            const float* sb = src + (size_t)b * kNV * 64;
            float aE = 0.f, aN = 0.f;
#pragma unroll
            for (int j = 0; j < 3; ++j) {
                int r = j * kNF + f;
                float gacc = 0.f;
#pragma unroll
                for (int k = 0; k < 3; ++k) {
                    int col   = Gc[r * 3 + k];
                    float val = Gv[r * 3 + k];
                    float xv  = sb[(size_t)col * 64 + lane];
                    if constexpr (BN) { xv = fmaf(xv, sc, sh); xv = xv > 0.f ? xv : 0.f; }
                    gacc = fmaf(val, xv, gacc);
                }
                aE = fmaf(gacc, ew[f * 3 + j], aE);
                aN = fmaf(gacc, ns[f * 3 + j], aN);
            }
            accE[t] = aE; accN[t] = aN;
        }
#pragma unroll
        for (int t = 0; t < 4; ++t)
            gegn[(size_t)(t0 + t) * 64 + lane] = packbf(accE[t], accN[t]);
    }
}

// ---------------- vertex kernel: meshconv finish + dense 64x256, 4 tasks/wave ----------------
template <bool STATS, bool BN>
__global__ __launch_bounds__(512, 2) void vertex_k(
    const float* __restrict__ src,                                   // (B,NV,64) pre-BN
    const unsigned* __restrict__ gegn,                               // (B*NF,64) bf16x2
    const int* __restrict__ Lc, const float* __restrict__ Lv,        // (NV,7)
    const int* __restrict__ Fc, const float* __restrict__ Fv,        // (NV,6)
    const float* __restrict__ coeffs, const float* __restrict__ bias,// (64,64,4),(64)
    const float* __restrict__ st, const float* __restrict__ bg, const float* __restrict__ bb,
    float* __restrict__ out, int outStride, float* __restrict__ stats)
{
    __shared__ __align__(16) uint2  cLds[64 * 64];    // [i2][o][half] bf16x4, 32 KB
    __shared__ __align__(16) float4 fLds[8 * 4 * 64]; // [wslot][t][i], 32 KB
    __shared__ float sred[STATS ? 8 * 128 : 8];
    int tid = threadIdx.x;
    for (int j = tid; j < 64 * 64; j += 512) {        // coeffs (o,i,k) -> [i2][o][i&1]
        int i = j & 63, o = j >> 6;
        float4 cf = *reinterpret_cast<const float4*>(coeffs + (size_t)(o * 64 + i) * 4);
        cLds[(i >> 1) * 128 + o * 2 + (i & 1)] = make_uint2(packbf(cf.x, cf.y), packbf(cf.z, cf.w));
    }
    __syncthreads();

    int lane  = tid & 63;
    int wslot = tid >> 6;
    int wave  = blockIdx.x * 8 + wslot;
    int nW    = gridDim.x * 8;
    float sc = 0.f, sh = 0.f;
    if constexpr (BN) {
        float m   = st[lane] * kInvN;
        float var = st[64 + lane] * kInvN - m * m;
        sc = bg[lane] * rsqrtf(var + kEPS);
        sh = bb[lane] - m * sc;
    }
    const float bo = bias[lane];
    float s = 0.f, sq = 0.f;
    float4* fme = fLds + wslot * 4 * 64;
    const uint4* cW = reinterpret_cast<const uint4*>(cLds);
    const int nG = kBNN / 4;  // 20481, exact

    for (int g = wave; g < nG; g += nW) {
        int t0 = g * 4;
#pragma unroll
        for (int t = 0; t < 4; ++t) {
            int task = t0 + t;
            int b = task >= kNV;
            int v = task - (b ? kNV : 0);
            const float* sb = src + (size_t)b * kNV * 64;
            const unsigned* gb = gegn + (size_t)b * kNF * 64;
            float xv = src[(size_t)task * 64 + lane];
            if constexpr (BN) { xv = fmaf(xv, sc, sh); xv = xv > 0.f ? xv : 0.f; }
            float lap = 0.f, gE = 0.f, gN = 0.f;
#pragma unroll
            for (int k = 0; k < 7; ++k) {
                int col = Lc[v * 7 + k];
                float xx = sb[(size_t)col * 64 + lane];
                if constexpr (BN) { xx = fmaf(xx, sc, sh); xx = xx > 0.f ? xx : 0.f; }
                lap = fmaf(Lv[v * 7 + k], xx, lap);
            }
#pragma unroll
            for (int k = 0; k < 6; ++k) {
                int col = Fc[v * 6 + k];
                float w = Fv[v * 6 + k];
                unsigned u = gb[(size_t)col * 64 + lane];
                gE = fmaf(w, bflo(u), gE);
                gN = fmaf(w, bfhi(u), gN);
            }
            fme[t * 64 + lane] = make_float4(xv, lap, gE, gN);
        }
        // intra-wave LDS write->read: in-order per wave, no barrier needed
        float a0 = bo, a1 = bo, a2 = bo, a3 = bo;
#pragma unroll 4
        for (int i2 = 0; i2 < 32; ++i2) {
            uint4 w = cW[i2 * 64 + lane];
            float wA0 = bflo(w.x), wA1 = bfhi(w.x), wA2 = bflo(w.y), wA3 = bfhi(w.y);
            float wB0 = bflo(w.z), wB1 = bfhi(w.z), wB2 = bflo(w.w), wB3 = bfhi(w.w);
            int ia = 2 * i2, ib = 2 * i2 + 1;
            float4 fa, fb;
            fa = fme[0 * 64 + ia]; fb = fme[0 * 64 + ib];
            a0 = fmaf(fa.x, wA0, a0); a0 = fmaf(fa.y, wA1, a0); a0 = fmaf(fa.z, wA2, a0); a0 = fmaf(fa.w, wA3, a0);
            a0 = fmaf(fb.x, wB0, a0); a0 = fmaf(fb.y, wB1, a0); a0 = fmaf(fb.z, wB2, a0); a0 = fmaf(fb.w, wB3, a0);
            fa = fme[1 * 64 + ia]; fb = fme[1 * 64 + ib];
            a1 = fmaf(fa.x, wA0, a1); a1 = fmaf(fa.y, wA1, a1); a1 = fmaf(fa.z, wA2, a1); a1 = fmaf(fa.w, wA3, a1);
            a1 = fmaf(fb.x, wB0, a1); a1 = fmaf(fb.y, wB1, a1); a1 = fmaf(fb.z, wB2, a1); a1 = fmaf(fb.w, wB3, a1);
            fa = fme[2 * 64 + ia]; fb = fme[2 * 64 + ib];
            a2 = fmaf(fa.x, wA0, a2); a2 = fmaf(fa.y, wA1, a2); a2 = fmaf(fa.z, wA2, a2); a2 = fmaf(fa.w, wA3, a2);
            a2 = fmaf(fb.x, wB0, a2); a2 = fmaf(fb.y, wB1, a2); a2 = fmaf(fb.z, wB2, a2); a2 = fmaf(fb.w, wB3, a2);
            fa = fme[3 * 64 + ia]; fb = fme[3 * 64 + ib];
            a3 = fmaf(fa.x, wA0, a3); a3 = fmaf(fa.y, wA1, a3); a3 = fmaf(fa.z, wA2, a3); a3 = fmaf(fa.w, wA3, a3);
            a3 = fmaf(fb.x, wB0, a3); a3 = fmaf(fb.y, wB1, a3); a3 = fmaf(fb.z, wB2, a3); a3 = fmaf(fb.w, wB3, a3);
        }
        out[(size_t)(t0 + 0) * outStride + lane] = a0;
        out[(size_t)(t0 + 1) * outStride + lane] = a1;
        out[(size_t)(t0 + 2) * outStride + lane] = a2;
        out[(size_t)(t0 + 3) * outStride + lane] = a3;
        if constexpr (STATS) {
            s  += a0 + a1 + a2 + a3;
            sq += a0 * a0 + a1 * a1 + a2 * a2 + a3 * a3;
        }
    }
    if constexpr (STATS) {
        sred[wslot * 128 + lane]      = s;
        sred[wslot * 128 + 64 + lane] = sq;
        __syncthreads();
        if (wslot == 0) {
            float S = 0.f, SQ = 0.f;
#pragma unroll
            for (int w = 0; w < 8; ++w) {
                S  += sred[w * 128 + lane];
                SQ += sred[w * 128 + 64 + lane];
            }
            atomicAdd(&stats[lane], S);
            atomicAdd(&stats[64 + lane], SQ);
        }
    }
}

// ---------------- 1x1 conv: 4 tasks/wave, bf16 weights in LDS, block-reduced stats ----------------
template <int CIN, bool DUAL, bool BN>
__global__ __launch_bounds__(512, 2) void pconv_k(
    const float* __restrict__ X,
    const float* __restrict__ stI, const float* __restrict__ gI, const float* __restrict__ bI,
    const float* __restrict__ W1, const float* __restrict__ b1,
    const float* __restrict__ W2, const float* __restrict__ b2,
    float* __restrict__ O1, float* __restrict__ O2,
    float* __restrict__ stats1, float* __restrict__ stats2)
{
    constexpr int CC = CIN / 4;
    __shared__ __align__(16) uint2  w1L[CC * 64];
    __shared__ __align__(16) uint2  w2L[DUAL ? CC * 64 : 1];
    __shared__ __align__(16) float4 xL[8 * 4 * CC];
    __shared__ float sred[DUAL ? 8 * 256 : 8 * 128];
    int tid = threadIdx.x;
    for (int j = tid; j < CC * 64; j += 512) {
        int cc = j & (CC - 1), o = j / CC;
        float4 wf = *reinterpret_cast<const float4*>(W1 + (size_t)o * CIN + cc * 4);
        w1L[(cc >> 1) * 128 + o * 2 + (cc & 1)] = make_uint2(packbf(wf.x, wf.y), packbf(wf.z, wf.w));
        if constexpr (DUAL) {
            float4 wg = *reinterpret_cast<const float4*>(W2 + (size_t)o * CIN + cc * 4);
            w2L[(cc >> 1) * 128 + o * 2 + (cc & 1)] = make_uint2(packbf(wg.x, wg.y), packbf(wg.z, wg.w));
        }
    }
    __syncthreads();

    int lane  = tid & 63;
    int wslot = tid >> 6;
    int wave  = blockIdx.x * 8 + wslot;
    int nW    = gridDim.x * 8;
    float scI = 0.f, shI = 0.f;
    if constexpr (BN) {  // only used with CIN==64
        float m   = stI[lane] * kInvN;
        float var = stI[64 + lane] * kInvN - m * m;
        scI = gI[lane] * rsqrtf(var + kEPS);
        shI = bI[lane] - m * scI;
    }
    const float bo1 = b1[lane];
    float bo2 = 0.f;
    if constexpr (DUAL) bo2 = b2[lane];
    float s1 = 0.f, sq1 = 0.f, s2 = 0.f, sq2 = 0.f;
    float* xme = reinterpret_cast<float*>(xL + wslot * 4 * CC);
    const float4* xme4 = xL + wslot * 4 * CC;
    const uint4* w1_4 = reinterpret_cast<const uint4*>(w1L);
    const uint4* w2_4 = reinterpret_cast<const uint4*>(w2L);
    const int nG = kBNN / 4;

    for (int g = wave; g < nG; g += nW) {
        int t0 = g * 4;
#pragma unroll
        for (int t = 0; t < 4; ++t) {
            int task = t0 + t;
            float xv = X[(size_t)task * CIN + lane];
            if constexpr (BN) { xv = fmaf(xv, scI, shI); xv = xv > 0.f ? xv : 0.f; }
            xme[t * CIN + lane] = xv;
            if constexpr (CIN == 128) xme[t * CIN + 64 + lane] = X[(size_t)task * CIN + 64 + lane];
        }
        float a1_[4] = {bo1, bo1, bo1, bo1};
        float a2_[4] = {bo2, bo2, bo2, bo2};
#pragma unroll 4
        for (int c2 = 0; c2 < CC / 2; ++c2) {
            uint4 u = w1_4[c2 * 64 + lane];
            float wA0 = bflo(u.x), wA1 = bfhi(u.x), wA2 = bflo(u.y), wA3 = bfhi(u.y);
            float wB0 = bflo(u.z), wB1 = bfhi(u.z), wB2 = bflo(u.w), wB3 = bfhi(u.w);
            int ca = 2 * c2, cb = 2 * c2 + 1;
#pragma unroll
            for (int t = 0; t < 4; ++t) {
                float4 xa = xme4[t * CC + ca], xb = xme4[t * CC + cb];
                a1_[t] = fmaf(xa.x, wA0, a1_[t]); a1_[t] = fmaf(xa.y, wA1, a1_[t]);
                a1_[t] = fmaf(xa.z, wA2, a1_[t]); a1_[t] = fmaf(xa.w, wA3, a1_[t]);
                a1_[t] = fmaf(xb.x, wB0, a1_[t]); a1_[t] = fmaf(xb.y, wB1, a1_[t]);
                a1_[t] = fmaf(xb.z, wB2, a1_[t]); a1_[t] = fmaf(xb.w, wB3, a1_[t]);
            }
            if constexpr (DUAL) {
                uint4 u2 = w2_4[c2 * 64 + lane];
                float qA0 = bflo(u2.x), qA1 = bfhi(u2.x), qA2 = bflo(u2.y), qA3 = bfhi(u2.y);
                float qB0 = bflo(u2.z), qB1 = bfhi(u2.z), qB2 = bflo(u2.w), qB3 = bfhi(u2.w);
#pragma unroll
                for (int t = 0; t < 4; ++t) {
                    float4 xa = xme4[t * CC + ca], xb = xme4[t * CC + cb];
                    a2_[t] = fmaf(xa.x, qA0, a2_[t]); a2_[t] = fmaf(xa.y, qA1, a2_[t]);
                    a2_[t] = fmaf(xa.z, qA2, a2_[t]); a2_[t] = fmaf(xa.w, qA3, a2_[t]);
                    a2_[t] = fmaf(xb.x, qB0, a2_[t]); a2_[t] = fmaf(xb.y, qB1, a2_[t]);
                    a2_[t] = fmaf(xb.z, qB2, a2_[t]); a2_[t] = fmaf(xb.w, qB3, a2_[t]);
                }
            }
        }
#pragma unroll
        for (int t = 0; t < 4; ++t) {
            float a = a1_[t];
            O1[(size_t)(t0 + t) * 64 + lane] = a;
            s1 += a; sq1 += a * a;
            if constexpr (DUAL) {
                float c = a2_[t];
                O2[(size_t)(t0 + t) * 64 + lane] = c;
                s2 += c; sq2 += c * c;
            }
        }
    }
    sred[wslot * 128 + lane]      = s1;
    sred[wslot * 128 + 64 + lane] = sq1;
    if constexpr (DUAL) {
        sred[1024 + wslot * 128 + lane]      = s2;
        sred[1024 + wslot * 128 + 64 + lane] = sq2;
    }
    __syncthreads();
    if (wslot == 0) {
        float S = 0.f, SQ = 0.f;
#pragma unroll
        for (int w = 0; w < 8; ++w) {
            S  += sred[w * 128 + lane];
            SQ += sred[w * 128 + 64 + lane];
        }
        atomicAdd(&stats1[lane], S);
        atomicAdd(&stats1[64 + lane], SQ);
    } else if (DUAL && wslot == 1) {
        float S = 0.f, SQ = 0.f;
#pragma unroll
        for (int w = 0; w < 8; ++w) {
            S  += sred[1024 + w * 128 + lane];
            SQ += sred[1024 + w * 128 + 64 + lane];
        }
        atomicAdd(&stats2[lane], S);
        atomicAdd(&stats2[64 + lane], SQ);
    }
}

// ---------------- final: relu(bn3(P3) + bns(S)) -> out (B,64,NV) channel-major ----------------
__global__ __launch_bounds__(256) void final_k(
    const float* __restrict__ P3, const float* __restrict__ S,
    const float* __restrict__ st3, const float* __restrict__ stS,
    const float* __restrict__ g3, const float* __restrict__ b3,
    const float* __restrict__ gs, const float* __restrict__ bs,
    float* __restrict__ out)
{
    __shared__ float lds[64 * 65];
    const int tilesPerB = (kNV + 63) / 64;  // 641
    int tile = blockIdx.x % tilesPerB;
    int b    = blockIdx.x / tilesPerB;
    int v0   = tile * 64;
    int tid  = threadIdx.x;
#pragma unroll
    for (int r = 0; r < 16; ++r) {
        int idx = r * 256 + tid;
        int vl = idx >> 6, o = idx & 63;
        int v = v0 + vl;
        if (v < kNV) {
            float m3  = st3[o] * kInvN;
            float vr3 = st3[64 + o] * kInvN - m3 * m3;
            float sc3 = g3[o] * rsqrtf(vr3 + kEPS);
            float sh3 = b3[o] - m3 * sc3;
            float mS  = stS[o] * kInvN;
            float vrS = stS[64 + o] * kInvN - mS * mS;
            float scS = gs[o] * rsqrtf(vrS + kEPS);
            float shS = bs[o] - mS * scS;
            size_t base = (size_t)(b * kNV + v) * 64 + o;
            float val = fmaf(P3[base], sc3, sh3) + fmaf(S[base], scS, shS);
            lds[vl * 65 + o] = val > 0.f ? val : 0.f;
        }
    }
    __syncthreads();
#pragma unroll
    for (int r = 0; r < 16; ++r) {
        int idx = r * 256 + tid;
        int o = idx >> 6, vl = idx & 63;
        int v = v0 + vl;
        if (v < kNV) out[(size_t)(b * 64 + o) * kNV + v] = lds[vl * 65 + o];
    }
}

extern "C" void kernel_launch(void* const* d_in, const int* in_sizes, int n_in,
                              void* d_out, int out_size, void* d_ws, size_t ws_size,
                              hipStream_t stream) {
    const float* x1  = (const float*)d_in[0];
    const float* x2  = (const float*)d_in[1];
    const int*   Gc  = (const int*)d_in[2];
    const float* Gv  = (const float*)d_in[3];
    const int*   Lc  = (const int*)d_in[4];
    const float* Lv  = (const float*)d_in[5];
    const int*   Fc  = (const int*)d_in[6];
    const float* Fv  = (const float*)d_in[7];
    const float* ew  = (const float*)d_in[8];
    const float* ns  = (const float*)d_in[9];
    // d_in[10] = v2p (identity arange, unused)
    const float* upC = (const float*)d_in[11];
    const float* upB = (const float*)d_in[12];
    const float* c2C = (const float*)d_in[13];
    const float* c2B = (const float*)d_in[14];
    const float* w1  = (const float*)d_in[15];
    const float* b1  = (const float*)d_in[16];
    const float* w3  = (const float*)d_in[17];
    const float* b3  = (const float*)d_in[18];
    const float* wsw = (const float*)d_in[19];
    const float* wsb = (const float*)d_in[20];
    const float* bn1g = (const float*)d_in[21];
    const float* bn1b = (const float*)d_in[22];
    const float* bn2g = (const float*)d_in[23];
    const float* bn2b = (const float*)d_in[24];
    const float* bn3g = (const float*)d_in[25];
    const float* bn3b = (const float*)d_in[26];
    const float* bnsg = (const float*)d_in[27];
    const float* bnsb = (const float*)d_in[28];

    float* ws = (float*)d_ws;
    float* stats = ws;  // [bn1|bn2|bn3|bns] x [sum64, sumsq64]
    size_t off = 512;
    float* xin_t = ws + off; off += (size_t)kB * kNV * 64;   // reused as P2
    float* X_t   = ws + off; off += (size_t)kB * kNV * 128;
    unsigned* gegn = (unsigned*)(ws + off); off += (size_t)kB * kNF * 64;
    float* P1    = ws + off; off += (size_t)kB * kNV * 64;   // reused as P3
    float* Sbuf  = ws + off; off += (size_t)kB * kNV * 64;
    float* P2 = xin_t;
    float* P3 = P1;
    float* out = (float*)d_out;

    zero_stats_k<<<1, 512, 0, stream>>>(stats);
    transpose_in_k<<<2 * 641, 256, 0, stream>>>(x1, x2, xin_t, X_t);
    // mesh_conv #1 (up) on xin
    face_k<false><<<2048, 256, 0, stream>>>(xin_t, Gc, Gv, ew, ns,
                                            nullptr, nullptr, nullptr, gegn);
    vertex_k<false, false><<<1024, 512, 0, stream>>>(xin_t, gegn, Lc, Lv, Fc, Fv, upC, upB,
                                                     nullptr, nullptr, nullptr,
                                                     X_t + 64, 128, nullptr);
    // conv1 + convs on X = [x2, xu]
    pconv_k<128, true, false><<<1024, 512, 0, stream>>>(X_t, nullptr, nullptr, nullptr,
                                                        w1, b1, wsw, wsb, P1, Sbuf,
                                                        stats + 0 * 128, stats + 3 * 128);
    // mesh_conv #2 (c2) on h = relu(bn1(P1)), BN fused into consumers
    face_k<true><<<2048, 256, 0, stream>>>(P1, Gc, Gv, ew, ns,
                                           stats + 0 * 128, bn1g, bn1b, gegn);
    vertex_k<true, true><<<1024, 512, 0, stream>>>(P1, gegn, Lc, Lv, Fc, Fv, c2C, c2B,
                                                   stats + 0 * 128, bn1g, bn1b,
                                                   P2, 64, stats + 1 * 128);
    // conv3 on h2 = relu(bn2(P2)), BN fused into input
    pconv_k<64, false, true><<<1024, 512, 0, stream>>>(P2, stats + 1 * 128, bn2g, bn2b,
                                                       w3, b3, nullptr, nullptr, P3, nullptr,
                                                       stats + 2 * 128, nullptr);
    final_k<<<2 * 641, 256, 0, stream>>>(P3, Sbuf, stats + 2 * 128, stats + 3 * 128,
                                         bn3g, bn3b, bnsg, bnsb, out);
}

// Round 4
// 330.790 us; speedup vs baseline: 3.1154x; 1.3244x over previous
//
#include <hip/hip_runtime.h>

typedef unsigned short u16;
typedef unsigned int u32;

constexpr int kNV  = 40962;
constexpr int kNF  = 81920;
constexpr int kNVP = 10242;
constexpr int kB   = 2;
constexpr float kEPS  = 1e-5f;
constexpr int kBNN   = kB * kNV;              // 81924
constexpr float kInvN = 1.0f / (float)kBNN;
constexpr int kTiles = (kBNN + 15) / 16;      // 5121

typedef __attribute__((ext_vector_type(8))) short bf16x8;
typedef __attribute__((ext_vector_type(4))) float f32x4;
union U4 { uint4 u; bf16x8 h; };

__device__ __forceinline__ float bflo(u32 u) { return __uint_as_float(u << 16); }
__device__ __forceinline__ float bfhi(u32 u) { return __uint_as_float(u & 0xffff0000u); }
__device__ __forceinline__ u32 packbf(float a, float b) {
    u32 ua = __float_as_uint(a), ub = __float_as_uint(b);
    ua += 0x7fffu + ((ua >> 16) & 1u);
    ub += 0x7fffu + ((ub >> 16) & 1u);
    return (ua >> 16) | (ub & 0xffff0000u);
}
__device__ __forceinline__ u16 bf16r(float a) {
    u32 ua = __float_as_uint(a);
    ua += 0x7fffu + ((ua >> 16) & 1u);
    return (u16)(ua >> 16);
}
__device__ __forceinline__ float b2f(u16 u) { return __uint_as_float(((u32)u) << 16); }

// ---------------- zero stats ----------------
__global__ void zero_stats_k(float* stats) {
    int t = threadIdx.x;
    if (t < 512) stats[t] = 0.f;
}

// ---------------- tiled transpose: x1 -> xin16 (ones-pad) bf16, x2 -> Xc[:, :64] bf16 ----------------
__global__ __launch_bounds__(256) void transpose_in_k(const float* __restrict__ x1,
                                                      const float* __restrict__ x2,
                                                      u16* __restrict__ xin16,
                                                      u16* __restrict__ Xc) {
    __shared__ float t1[64 * 65];
    __shared__ float t2[64 * 65];
    const int tilesPerB = (kNV + 63) / 64;  // 641
    int tile = blockIdx.x % tilesPerB;
    int b    = blockIdx.x / tilesPerB;
    int v0   = tile * 64;
    int tid  = threadIdx.x;
    bool hasX1 = v0 < kNVP;
#pragma unroll
    for (int r = 0; r < 16; ++r) {
        int idx = r * 256 + tid;
        int c = idx >> 6, vl = idx & 63;
        int v = v0 + vl;
        if (v < kNV) {
            t2[vl * 65 + c] = x2[(size_t)(b * 64 + c) * kNV + v];
            if (hasX1) t1[vl * 65 + c] = (v < kNVP) ? x1[(size_t)(b * 64 + c) * kNVP + v] : 1.0f;
        }
    }
    __syncthreads();
#pragma unroll
    for (int r = 0; r < 16; ++r) {
        int idx = r * 256 + tid;
        int vl = idx >> 6, c = idx & 63;
        int v = v0 + vl;
        if (v < kNV) {
            Xc[(size_t)(b * kNV + v) * 128 + c]   = bf16r(t2[vl * 65 + c]);
            xin16[(size_t)(b * kNV + v) * 64 + c] = hasX1 ? bf16r(t1[vl * 65 + c]) : (u16)0x3f80;
        }
    }
}

// ---------------- face kernel: packed bf16 (ge,gn), optional fused BN+ReLU, bf16 or f32 src ----------------
template <bool BN, bool S16>
__global__ __launch_bounds__(256) void face_k(
    const void* __restrict__ src_,                                   // (B,NV,64)
    const int* __restrict__ Gc, const float* __restrict__ Gv,        // (3NF,3)
    const float* __restrict__ ew, const float* __restrict__ ns,      // (NF,3)
    const float* __restrict__ st, const float* __restrict__ bg, const float* __restrict__ bb,
    u32* __restrict__ gegn)                                          // (B*NF,64) bf16x2
{
    int lane = threadIdx.x & 63;
    int wave = blockIdx.x * 4 + (threadIdx.x >> 6);
    int nW   = gridDim.x * 4;
    float sc = 0.f, sh = 0.f;
    if constexpr (BN) {
        float m   = st[lane] * kInvN;
        float var = st[64 + lane] * kInvN - m * m;
        sc = bg[lane] * rsqrtf(var + kEPS);
        sh = bb[lane] - m * sc;
    }
    const int nG = (kB * kNF) / 4;  // 40960, exact
    for (int g = wave; g < nG; g += nW) {
        int t0 = g * 4;
        float accE[4], accN[4];
#pragma unroll
        for (int t = 0; t < 4; ++t) {
            int task = t0 + t;
            int b = task >= kNF;
            int f = task - (b ? kNF : 0);
            float aE = 0.f, aN = 0.f;
#pragma unroll
            for (int j = 0; j < 3; ++j) {
                int r = j * kNF + f;
                float gacc = 0.f;
#pragma unroll
                for (int k = 0; k < 3; ++k) {
                    int col   = Gc[r * 3 + k];
                    float val = Gv[r * 3 + k];
                    float xv;
                    if constexpr (S16) {
                        const u16* sb = (const u16*)src_ + (size_t)b * kNV * 64;
                        xv = b2f(sb[(size_t)col * 64 + lane]);
                    } else {
                        const float* sb = (const float*)src_ + (size_t)b * kNV * 64;
                        xv = sb[(size_t)col * 64 + lane];
                    }
                    if constexpr (BN) { xv = fmaf(xv, sc, sh); xv = xv > 0.f ? xv : 0.f; }
                    gacc = fmaf(val, xv, gacc);
                }
                aE = fmaf(gacc, ew[f * 3 + j], aE);
                aN = fmaf(gacc, ns[f * 3 + j], aN);
            }
            accE[t] = aE; accN[t] = aN;
        }
#pragma unroll
        for (int t = 0; t < 4; ++t)
            gegn[(size_t)(t0 + t) * 64 + lane] = packbf(accE[t], accN[t]);
    }
}

// ---------------- vertex kernel: gathers -> feat LDS -> MFMA 16x16x32 bf16 ----------------
// GEMM: M=tasks(16/wave), N=64, K=256 (=64 ch x {x,lap,gE,gN})
template <bool STATS, bool BN, bool SRC16, bool OUT16>
__global__ __launch_bounds__(512) void vertex_mfma_k(
    const void* __restrict__ src_,                                   // (B,NV,64)
    const u32* __restrict__ gegn,                                    // (B*NF,64)
    const int* __restrict__ Lc, const float* __restrict__ Lv,        // (NV,7)
    const int* __restrict__ Fc, const float* __restrict__ Fv,        // (NV,6)
    const float* __restrict__ coeffs, const float* __restrict__ bias,// (64,64,4),(64)
    const float* __restrict__ st, const float* __restrict__ bg, const float* __restrict__ bbn,
    void* __restrict__ out_, int outStride, float* __restrict__ stats)
{
    __shared__ __align__(16) u16 Bl[256 * 64];        // 32 KB, swizzled bf16 weights
    __shared__ __align__(16) uint2 feat[8][16][64];   // 64 KB, [wslot][t][i^((t&3)<<3)]
    __shared__ float sred[STATS ? 8 * 128 : 4];

    int tid = threadIdx.x;
    for (int idx = tid; idx < 256 * 64; idx += 512) {
        int k = idx >> 6, col = idx & 63;
        int s = k >> 5, kg = (k >> 3) & 3, jj = k & 7;
        float v = coeffs[((size_t)col * 64 + (k >> 2)) * 4 + (k & 3)];
        Bl[((s * 4 + kg) * 64 + (col ^ kg)) * 8 + jj] = bf16r(v);
    }
    __syncthreads();

    int lane  = tid & 63;
    int wslot = tid >> 6;
    float sc = 0.f, sh = 0.f;
    if constexpr (BN) {
        float m   = st[lane] * kInvN;
        float var = st[64 + lane] * kInvN - m * m;
        sc = bg[lane] * rsqrtf(var + kEPS);
        sh = bbn[lane] - m * sc;
    }
    int tA = lane & 15, kg = lane >> 4;
    const int amask = (tA & 3) << 3;
    float bias_w[4];
#pragma unroll
    for (int nf = 0; nf < 4; ++nf) bias_w[nf] = bias[nf * 16 + tA];
    float s_[4] = {0.f, 0.f, 0.f, 0.f}, sq_[4] = {0.f, 0.f, 0.f, 0.f};

    int wave = blockIdx.x * 8 + wslot;
    int nW   = gridDim.x * 8;

    for (int tile = wave; tile < kTiles; tile += nW) {
        int base = tile * 16;
        // ---- gather phase: lane = channel ----
#pragma unroll 4
        for (int t = 0; t < 16; ++t) {
            int task = base + t;
            float x0 = 0.f, lap = 0.f, gE = 0.f, gN = 0.f;
            if (task < kBNN) {
                int b = task >= kNV;
                int v = task - (b ? kNV : 0);
                const u32* gb = gegn + (size_t)b * kNF * 64;
                if constexpr (SRC16) {
                    const u16* s16 = (const u16*)src_;
                    const u16* sb = s16 + (size_t)b * kNV * 64;
                    x0 = b2f(s16[(size_t)task * 64 + lane]);
#pragma unroll
                    for (int k = 0; k < 7; ++k)
                        lap = fmaf(Lv[v * 7 + k], b2f(sb[(size_t)Lc[v * 7 + k] * 64 + lane]), lap);
                } else {
                    const float* sf = (const float*)src_;
                    const float* sb = sf + (size_t)b * kNV * 64;
                    float xv = sf[(size_t)task * 64 + lane];
                    if constexpr (BN) { xv = fmaf(xv, sc, sh); xv = xv > 0.f ? xv : 0.f; }
                    x0 = xv;
#pragma unroll
                    for (int k = 0; k < 7; ++k) {
                        float xx = sb[(size_t)Lc[v * 7 + k] * 64 + lane];
                        if constexpr (BN) { xx = fmaf(xx, sc, sh); xx = xx > 0.f ? xx : 0.f; }
                        lap = fmaf(Lv[v * 7 + k], xx, lap);
                    }
                }
#pragma unroll
                for (int k = 0; k < 6; ++k) {
                    u32 u = gb[(size_t)Fc[v * 6 + k] * 64 + lane];
                    float w = Fv[v * 6 + k];
                    gE = fmaf(w, bflo(u), gE);
                    gN = fmaf(w, bfhi(u), gN);
                }
            }
            feat[wslot][t][lane ^ ((t & 3) << 3)] = make_uint2(packbf(x0, lap), packbf(gE, gN));
        }
        // ---- MFMA phase (intra-wave LDS, no barrier) ----
        f32x4 z = {0.f, 0.f, 0.f, 0.f};
        f32x4 acc[4]; acc[0] = z; acc[1] = z; acc[2] = z; acc[3] = z;
#pragma unroll
        for (int s = 0; s < 8; ++s) {
            int i0 = s * 8 + kg * 2;
            U4 a; a.u = *(const uint4*)&feat[wslot][tA][i0 ^ amask];
#pragma unroll
            for (int nf = 0; nf < 4; ++nf) {
                int colb = nf * 16 + tA;
                U4 bb; bb.u = *(const uint4*)&Bl[((s * 4 + kg) * 64 + (colb ^ kg)) * 8];
                acc[nf] = __builtin_amdgcn_mfma_f32_16x16x32_bf16(a.h, bb.h, acc[nf], 0, 0, 0);
            }
        }
        // ---- write phase: D row = kg*4+r, col = nf*16+tA ----
#pragma unroll
        for (int nf = 0; nf < 4; ++nf) {
#pragma unroll
            for (int r = 0; r < 4; ++r) {
                int task = base + kg * 4 + r;
                if (task < kBNN) {
                    float val = acc[nf][r] + bias_w[nf];
                    int col = nf * 16 + tA;
                    if constexpr (OUT16)
                        ((u16*)out_)[(size_t)task * outStride + col] = bf16r(val);
                    else
                        ((float*)out_)[(size_t)task * outStride + col] = val;
                    if constexpr (STATS) { s_[nf] += val; sq_[nf] += val * val; }
                }
            }
        }
    }
    if constexpr (STATS) {
#pragma unroll
        for (int nf = 0; nf < 4; ++nf) {
            s_[nf]  += __shfl_xor(s_[nf], 16, 64);  s_[nf]  += __shfl_xor(s_[nf], 32, 64);
            sq_[nf] += __shfl_xor(sq_[nf], 16, 64); sq_[nf] += __shfl_xor(sq_[nf], 32, 64);
        }
        if (lane < 16) {
#pragma unroll
            for (int nf = 0; nf < 4; ++nf) {
                sred[wslot * 128 + nf * 16 + lane]      = s_[nf];
                sred[wslot * 128 + 64 + nf * 16 + lane] = sq_[nf];
            }
        }
        __syncthreads();
        if (wslot == 0) {
            float S = 0.f, SQ = 0.f;
#pragma unroll
            for (int w = 0; w < 8; ++w) {
                S  += sred[w * 128 + lane];
                SQ += sred[w * 128 + 64 + lane];
            }
            atomicAdd(&stats[lane], S);
            atomicAdd(&stats[64 + lane], SQ);
        }
    }
}

// ---------------- conv1+convs fused: A=Xc bf16 global, N=128 (64|64), K=128, MFMA ----------------
__global__ __launch_bounds__(512) void pconv_dual_k(
    const u16* __restrict__ Xc,
    const float* __restrict__ W1, const float* __restrict__ b1,
    const float* __restrict__ W2, const float* __restrict__ b2,
    float* __restrict__ O1, float* __restrict__ O2,
    float* __restrict__ stats1, float* __restrict__ stats2)
{
    __shared__ __align__(16) u16 Bl[128 * 128];   // 32 KB
    __shared__ float sred[8 * 256];
    int tid = threadIdx.x;
    for (int idx = tid; idx < 128 * 128; idx += 512) {
        int k = idx >> 7, col = idx & 127;
        int s = k >> 5, kg = (k >> 3) & 3, jj = k & 7;
        float v = (col < 64) ? W1[(size_t)col * 128 + k] : W2[(size_t)(col - 64) * 128 + k];
        Bl[((s * 4 + kg) * 128 + (col ^ kg)) * 8 + jj] = bf16r(v);
    }
    __syncthreads();

    int lane = tid & 63, wslot = tid >> 6;
    int tA = lane & 15, kg = lane >> 4;
    float bias_w[8];
#pragma unroll
    for (int nf = 0; nf < 8; ++nf)
        bias_w[nf] = (nf < 4) ? b1[nf * 16 + tA] : b2[(nf - 4) * 16 + tA];
    float s_[8] = {0.f}, sq_[8] = {0.f};

    int wave = blockIdx.x * 8 + wslot;
    int nW   = gridDim.x * 8;
    for (int tile = wave; tile < kTiles; tile += nW) {
        int base = tile * 16;
        int taskA = min(base + tA, kBNN - 1);
        f32x4 zz = {0.f, 0.f, 0.f, 0.f};
        f32x4 acc[8];
#pragma unroll
        for (int nf = 0; nf < 8; ++nf) acc[nf] = zz;
#pragma unroll
        for (int s = 0; s < 4; ++s) {
            U4 a; a.u = *(const uint4*)&Xc[(size_t)taskA * 128 + s * 32 + kg * 8];
#pragma unroll
            for (int nf = 0; nf < 8; ++nf) {
                int colb = nf * 16 + tA;
                U4 bb; bb.u = *(const uint4*)&Bl[((s * 4 + kg) * 128 + (colb ^ kg)) * 8];
                acc[nf] = __builtin_amdgcn_mfma_f32_16x16x32_bf16(a.h, bb.h, acc[nf], 0, 0, 0);
            }
        }
#pragma unroll
        for (int nf = 0; nf < 8; ++nf) {
#pragma unroll
            for (int r = 0; r < 4; ++r) {
                int task = base + kg * 4 + r;
                if (task < kBNN) {
                    float val = acc[nf][r] + bias_w[nf];
                    if (nf < 4) O1[(size_t)task * 64 + nf * 16 + tA] = val;
                    else        O2[(size_t)task * 64 + (nf - 4) * 16 + tA] = val;
                    s_[nf] += val; sq_[nf] += val * val;
                }
            }
        }
    }
#pragma unroll
    for (int nf = 0; nf < 8; ++nf) {
        s_[nf]  += __shfl_xor(s_[nf], 16, 64);  s_[nf]  += __shfl_xor(s_[nf], 32, 64);
        sq_[nf] += __shfl_xor(sq_[nf], 16, 64); sq_[nf] += __shfl_xor(sq_[nf], 32, 64);
    }
    if (lane < 16) {
#pragma unroll
        for (int nf = 0; nf < 8; ++nf) {
            sred[wslot * 256 + nf * 16 + lane]       = s_[nf];
            sred[wslot * 256 + 128 + nf * 16 + lane] = sq_[nf];
        }
    }
    __syncthreads();
    if (wslot == 0) {
        float S = 0.f, SQ = 0.f;
#pragma unroll
        for (int w = 0; w < 8; ++w) {
            S  += sred[w * 256 + lane];
            SQ += sred[w * 256 + 128 + lane];
        }
        atomicAdd(&stats1[lane], S);
        atomicAdd(&stats1[64 + lane], SQ);
    } else if (wslot == 1) {
        float S = 0.f, SQ = 0.f;
#pragma unroll
        for (int w = 0; w < 8; ++w) {
            S  += sred[w * 256 + 64 + lane];
            SQ += sred[w * 256 + 128 + 64 + lane];
        }
        atomicAdd(&stats2[lane], S);
        atomicAdd(&stats2[64 + lane], SQ);
    }
}

// ---------------- conv3: A = relu(bn2(P2)) built on the fly, K=64, N=64, MFMA ----------------
__global__ __launch_bounds__(512) void pconv3_k(
    const float* __restrict__ P2,
    const float* __restrict__ st2, const float* __restrict__ g2, const float* __restrict__ b2n,
    const float* __restrict__ W, const float* __restrict__ bW,
    float* __restrict__ O, float* __restrict__ stats)
{
    __shared__ __align__(16) u16 Bl[64 * 64];   // 8 KB
    __shared__ float sred[8 * 128];
    int tid = threadIdx.x;
    for (int idx = tid; idx < 64 * 64; idx += 512) {
        int k = idx >> 6, col = idx & 63;
        int s = k >> 5, kg = (k >> 3) & 3, jj = k & 7;
        Bl[((s * 4 + kg) * 64 + (col ^ kg)) * 8 + jj] = bf16r(W[(size_t)col * 64 + k]);
    }
    __syncthreads();

    int lane = tid & 63, wslot = tid >> 6;
    int tA = lane & 15, kg = lane >> 4;
    float scA[2][8], shA[2][8];
#pragma unroll
    for (int s = 0; s < 2; ++s)
#pragma unroll
        for (int j = 0; j < 8; ++j) {
            int ch = s * 32 + kg * 8 + j;
            float m   = st2[ch] * kInvN;
            float var = st2[64 + ch] * kInvN - m * m;
            float sc  = g2[ch] * rsqrtf(var + kEPS);
            scA[s][j] = sc;
            shA[s][j] = b2n[ch] - m * sc;
        }
    float bias_w[4];
#pragma unroll
    for (int nf = 0; nf < 4; ++nf) bias_w[nf] = bW[nf * 16 + tA];
    float s_[4] = {0.f}, sq_[4] = {0.f};

    int wave = blockIdx.x * 8 + wslot;
    int nW   = gridDim.x * 8;
    for (int tile = wave; tile < kTiles; tile += nW) {
        int base = tile * 16;
        int taskA = min(base + tA, kBNN - 1);
        f32x4 zz = {0.f, 0.f, 0.f, 0.f};
        f32x4 acc[4]; acc[0] = zz; acc[1] = zz; acc[2] = zz; acc[3] = zz;
#pragma unroll
        for (int s = 0; s < 2; ++s) {
            const float4* p = (const float4*)&P2[(size_t)taskA * 64 + s * 32 + kg * 8];
            float4 pa = p[0], pb = p[1];
            float xv[8] = {pa.x, pa.y, pa.z, pa.w, pb.x, pb.y, pb.z, pb.w};
            u32 w0, w1, w2, w3;
            {
                float t0, t1;
                t0 = fmaf(xv[0], scA[s][0], shA[s][0]); t0 = t0 > 0.f ? t0 : 0.f;
                t1 = fmaf(xv[1], scA[s][1], shA[s][1]); t1 = t1 > 0.f ? t1 : 0.f;
                w0 = packbf(t0, t1);
                t0 = fmaf(xv[2], scA[s][2], shA[s][2]); t0 = t0 > 0.f ? t0 : 0.f;
                t1 = fmaf(xv[3], scA[s][3], shA[s][3]); t1 = t1 > 0.f ? t1 : 0.f;
                w1 = packbf(t0, t1);
                t0 = fmaf(xv[4], scA[s][4], shA[s][4]); t0 = t0 > 0.f ? t0 : 0.f;
                t1 = fmaf(xv[5], scA[s][5], shA[s][5]); t1 = t1 > 0.f ? t1 : 0.f;
                w2 = packbf(t0, t1);
                t0 = fmaf(xv[6], scA[s][6], shA[s][6]); t0 = t0 > 0.f ? t0 : 0.f;
                t1 = fmaf(xv[7], scA[s][7], shA[s][7]); t1 = t1 > 0.f ? t1 : 0.f;
                w3 = packbf(t0, t1);
            }
            U4 a; a.u = make_uint4(w0, w1, w2, w3);
#pragma unroll
            for (int nf = 0; nf < 4; ++nf) {
                int colb = nf * 16 + tA;
                U4 bb; bb.u = *(const uint4*)&Bl[((s * 4 + kg) * 64 + (colb ^ kg)) * 8];
                acc[nf] = __builtin_amdgcn_mfma_f32_16x16x32_bf16(a.h, bb.h, acc[nf], 0, 0, 0);
            }
        }
#pragma unroll
        for (int nf = 0; nf < 4; ++nf) {
#pragma unroll
            for (int r = 0; r < 4; ++r) {
                int task = base + kg * 4 + r;
                if (task < kBNN) {
                    float val = acc[nf][r] + bias_w[nf];
                    O[(size_t)task * 64 + nf * 16 + tA] = val;
                    s_[nf] += val; sq_[nf] += val * val;
                }
            }
        }
    }
#pragma unroll
    for (int nf = 0; nf < 4; ++nf) {
        s_[nf]  += __shfl_xor(s_[nf], 16, 64);  s_[nf]  += __shfl_xor(s_[nf], 32, 64);
        sq_[nf] += __shfl_xor(sq_[nf], 16, 64); sq_[nf] += __shfl_xor(sq_[nf], 32, 64);
    }
    if (lane < 16) {
#pragma unroll
        for (int nf = 0; nf < 4; ++nf) {
            sred[wslot * 128 + nf * 16 + lane]      = s_[nf];
            sred[wslot * 128 + 64 + nf * 16 + lane] = sq_[nf];
        }
    }
    __syncthreads();
    if (wslot == 0) {
        float S = 0.f, SQ = 0.f;
#pragma unroll
        for (int w = 0; w < 8; ++w) {
            S  += sred[w * 128 + lane];
            SQ += sred[w * 128 + 64 + lane];
        }
        atomicAdd(&stats[lane], S);
        atomicAdd(&stats[64 + lane], SQ);
    }
}

// ---------------- final: relu(bn3(P3) + bns(S)) -> out (B,64,NV) channel-major ----------------
__global__ __launch_bounds__(256) void final_k(
    const float* __restrict__ P3, const float* __restrict__ S,
    const float* __restrict__ st3, const float* __restrict__ stS,
    const float* __restrict__ g3, const float* __restrict__ b3,
    const float* __restrict__ gs, const float* __restrict__ bs,
    float* __restrict__ out)
{
    __shared__ float lds[64 * 65];
    const int tilesPerB = (kNV + 63) / 64;  // 641
    int tile = blockIdx.x % tilesPerB;
    int b    = blockIdx.x / tilesPerB;
    int v0   = tile * 64;
    int tid  = threadIdx.x;
#pragma unroll
    for (int r = 0; r < 16; ++r) {
        int idx = r * 256 + tid;
        int vl = idx >> 6, o = idx & 63;
        int v = v0 + vl;
        if (v < kNV) {
            float m3  = st3[o] * kInvN;
            float vr3 = st3[64 + o] * kInvN - m3 * m3;
            float sc3 = g3[o] * rsqrtf(vr3 + kEPS);
            float sh3 = b3[o] - m3 * sc3;
            float mS  = stS[o] * kInvN;
            float vrS = stS[64 + o] * kInvN - mS * mS;
            float scS = gs[o] * rsqrtf(vrS + kEPS);
            float shS = bs[o] - mS * scS;
            size_t base = (size_t)(b * kNV + v) * 64 + o;
            float val = fmaf(P3[base], sc3, sh3) + fmaf(S[base], scS, shS);
            lds[vl * 65 + o] = val > 0.f ? val : 0.f;
        }
    }
    __syncthreads();
#pragma unroll
    for (int r = 0; r < 16; ++r) {
        int idx = r * 256 + tid;
        int o = idx >> 6, vl = idx & 63;
        int v = v0 + vl;
        if (v < kNV) out[(size_t)(b * 64 + o) * kNV + v] = lds[vl * 65 + o];
    }
}

extern "C" void kernel_launch(void* const* d_in, const int* in_sizes, int n_in,
                              void* d_out, int out_size, void* d_ws, size_t ws_size,
                              hipStream_t stream) {
    const float* x1  = (const float*)d_in[0];
    const float* x2  = (const float*)d_in[1];
    const int*   Gc  = (const int*)d_in[2];
    const float* Gv  = (const float*)d_in[3];
    const int*   Lc  = (const int*)d_in[4];
    const float* Lv  = (const float*)d_in[5];
    const int*   Fc  = (const int*)d_in[6];
    const float* Fv  = (const float*)d_in[7];
    const float* ew  = (const float*)d_in[8];
    const float* ns  = (const float*)d_in[9];
    // d_in[10] = v2p (identity arange, unused)
    const float* upC = (const float*)d_in[11];
    const float* upB = (const float*)d_in[12];
    const float* c2C = (const float*)d_in[13];
    const float* c2B = (const float*)d_in[14];
    const float* w1  = (const float*)d_in[15];
    const float* b1  = (const float*)d_in[16];
    const float* w3  = (const float*)d_in[17];
    const float* b3  = (const float*)d_in[18];
    const float* wsw = (const float*)d_in[19];
    const float* wsb = (const float*)d_in[20];
    const float* bn1g = (const float*)d_in[21];
    const float* bn1b = (const float*)d_in[22];
    const float* bn2g = (const float*)d_in[23];
    const float* bn2b = (const float*)d_in[24];
    const float* bn3g = (const float*)d_in[25];
    const float* bn3b = (const float*)d_in[26];
    const float* bnsg = (const float*)d_in[27];
    const float* bnsb = (const float*)d_in[28];

    float* ws = (float*)d_ws;
    float* stats = ws;  // [bn1|bn2|bn3|bns] x [sum64, sumsq64]
    size_t off = 512;
    u16* Xc     = (u16*)(ws + off); off += (size_t)kBNN * 64;   // bf16 (B*NV,128)
    u16* xin16  = (u16*)(ws + off); off += (size_t)kBNN * 32;   // bf16 (B*NV,64)
    u32* gegn   = (u32*)(ws + off); off += (size_t)kB * kNF * 64;
    float* P1   = ws + off; off += (size_t)kBNN * 64;
    float* Sbuf = ws + off; off += (size_t)kBNN * 64;
    float* P2   = ws + off; off += (size_t)kBNN * 64;
    float* P3   = ws + off; off += (size_t)kBNN * 64;
    float* out = (float*)d_out;

    zero_stats_k<<<1, 512, 0, stream>>>(stats);
    transpose_in_k<<<2 * 641, 256, 0, stream>>>(x1, x2, xin16, Xc);
    // mesh_conv #1 (up) on xin (bf16 src), output -> Xc[:, 64:128] bf16
    face_k<false, true><<<2048, 256, 0, stream>>>(xin16, Gc, Gv, ew, ns,
                                                  nullptr, nullptr, nullptr, gegn);
    vertex_mfma_k<false, false, true, true><<<256, 512, 0, stream>>>(
        xin16, gegn, Lc, Lv, Fc, Fv, upC, upB, nullptr, nullptr, nullptr,
        (void*)(Xc + 64), 128, nullptr);
    // conv1 + convs on X = [x2, xu] (bf16)
    pconv_dual_k<<<512, 512, 0, stream>>>(Xc, w1, b1, wsw, wsb, P1, Sbuf,
                                          stats + 0 * 128, stats + 3 * 128);
    // mesh_conv #2 (c2) on h = relu(bn1(P1)), BN fused into consumers
    face_k<true, false><<<2048, 256, 0, stream>>>(P1, Gc, Gv, ew, ns,
                                                  stats + 0 * 128, bn1g, bn1b, gegn);
    vertex_mfma_k<true, true, false, false><<<256, 512, 0, stream>>>(
        P1, gegn, Lc, Lv, Fc, Fv, c2C, c2B, stats + 0 * 128, bn1g, bn1b,
        P2, 64, stats + 1 * 128);
    // conv3 on h2 = relu(bn2(P2)), BN fused into A-fragment build
    pconv3_k<<<512, 512, 0, stream>>>(P2, stats + 1 * 128, bn2g, bn2b,
                                      w3, b3, P3, stats + 2 * 128);
    final_k<<<2 * 641, 256, 0, stream>>>(P3, Sbuf, stats + 2 * 128, stats + 3 * 128,
                                         bn3g, bn3b, bnsg, bnsb, out);
}